// Round 1
// baseline (169.472 us; speedup 1.0000x reference)
//
#include <hip/hip_runtime.h>

#define NE    7
#define DD    64
#define NDC   3
#define BLOCK 256
#define CHUNK 1536

// Grid: (ceil(B/CHUNK), NE). Each block gathers rows of its chunk whose
// size_idx == blockIdx.y into an LDS list (block-uniform expert => scalar
// weight loads), then computes the 3-layer MLP thread-per-row with 64
// statically-indexed fp32 accumulators (VALU, 64-way ILP).
__global__ __launch_bounds__(BLOCK) void moe_routed_kernel(
    const float* __restrict__ X,
    const int*   __restrict__ S,
    const float* __restrict__ W1, const float* __restrict__ B1,
    const float* __restrict__ W2, const float* __restrict__ B2,
    const float* __restrict__ W3, const float* __restrict__ B3,
    float* __restrict__ out, int B)
{
    __shared__ int   list[CHUNK];
    __shared__ int   cnt;
    __shared__ float hbuf[DD][BLOCK];   // h1 staging: read with dynamic k, 2-way banks (free)

    const int e    = blockIdx.y;
    const int tid  = threadIdx.x;
    const int base = blockIdx.x * CHUNK;

    if (tid == 0) cnt = 0;
    __syncthreads();

    const int lim = min(CHUNK, B - base);
    for (int i = tid; i < lim; i += BLOCK) {
        const int row = base + i;
        if (S[row] == e) {
            const int p = atomicAdd(&cnt, 1);
            list[p] = row;
        }
    }
    __syncthreads();
    const int n = cnt;

    const float* __restrict__ W1e = W1 + e * DD * DD;
    const float* __restrict__ W2e = W2 + e * DD * DD;
    const float* __restrict__ W3e = W3 + e * DD * NDC;
    const float* __restrict__ B1e = B1 + e * DD;
    const float* __restrict__ B2e = B2 + e * DD;
    const float* __restrict__ B3e = B3 + e * NDC;

    for (int r = tid; r < n; r += BLOCK) {
        const int row = list[r];
        const float4* __restrict__ xp =
            reinterpret_cast<const float4*>(X + (size_t)row * DD);

        float acc[DD];
        #pragma unroll
        for (int j = 0; j < DD; ++j) acc[j] = B1e[j];

        // ---- layer 1: h1 = relu(x @ W1 + b1) ----
        #pragma unroll 1
        for (int g = 0; g < DD / 4; ++g) {
            const float4 xv = xp[g];                    // per-lane vector load
            const float* __restrict__ w = W1e + g * 4 * DD;  // uniform -> s_load
            #pragma unroll
            for (int j = 0; j < DD; ++j) acc[j] = fmaf(xv.x, w[j],          acc[j]);
            #pragma unroll
            for (int j = 0; j < DD; ++j) acc[j] = fmaf(xv.y, w[DD + j],     acc[j]);
            #pragma unroll
            for (int j = 0; j < DD; ++j) acc[j] = fmaf(xv.z, w[2 * DD + j], acc[j]);
            #pragma unroll
            for (int j = 0; j < DD; ++j) acc[j] = fmaf(xv.w, w[3 * DD + j], acc[j]);
        }

        // stage relu(h1) in LDS so layer 2 can read it with a runtime k index
        #pragma unroll
        for (int j = 0; j < DD; ++j) hbuf[j][tid] = fmaxf(acc[j], 0.0f);

        // ---- layer 2: h2 = relu(h1 @ W2 + b2) ----
        #pragma unroll
        for (int j = 0; j < DD; ++j) acc[j] = B2e[j];

        #pragma unroll 1
        for (int g = 0; g < DD / 4; ++g) {
            const float h0 = hbuf[4 * g + 0][tid];
            const float h1 = hbuf[4 * g + 1][tid];
            const float h2 = hbuf[4 * g + 2][tid];
            const float h3 = hbuf[4 * g + 3][tid];
            const float* __restrict__ w = W2e + g * 4 * DD;  // uniform -> s_load
            #pragma unroll
            for (int j = 0; j < DD; ++j) acc[j] = fmaf(h0, w[j],          acc[j]);
            #pragma unroll
            for (int j = 0; j < DD; ++j) acc[j] = fmaf(h1, w[DD + j],     acc[j]);
            #pragma unroll
            for (int j = 0; j < DD; ++j) acc[j] = fmaf(h2, w[2 * DD + j], acc[j]);
            #pragma unroll
            for (int j = 0; j < DD; ++j) acc[j] = fmaf(h3, w[3 * DD + j], acc[j]);
        }

        // ---- layer 3: logits = relu(h2) @ W3 + b3 (static k unroll) ----
        float l0 = B3e[0], l1 = B3e[1], l2 = B3e[2];
        #pragma unroll
        for (int k = 0; k < DD; ++k) {
            const float h = fmaxf(acc[k], 0.0f);
            l0 = fmaf(h, W3e[k * 3 + 0], l0);
            l1 = fmaf(h, W3e[k * 3 + 1], l1);
            l2 = fmaf(h, W3e[k * 3 + 2], l2);
        }

        // ---- softmax over 3 classes ----
        const float m  = fmaxf(l0, fmaxf(l1, l2));
        const float p0 = __expf(l0 - m);
        const float p1 = __expf(l1 - m);
        const float p2 = __expf(l2 - m);
        const float inv = 1.0f / (p0 + p1 + p2);

        const size_t o = (size_t)row * 3;
        out[o + 0] = l0;
        out[o + 1] = l1;
        out[o + 2] = l2;
        float* __restrict__ pr = out + (size_t)B * 3;
        pr[o + 0] = p0 * inv;
        pr[o + 1] = p1 * inv;
        pr[o + 2] = p2 * inv;
    }
}

extern "C" void kernel_launch(void* const* d_in, const int* in_sizes, int n_in,
                              void* d_out, int out_size, void* d_ws, size_t ws_size,
                              hipStream_t stream)
{
    const float* X  = (const float*)d_in[0];
    const int*   S  = (const int*)d_in[1];
    const float* W1 = (const float*)d_in[2];
    const float* B1 = (const float*)d_in[3];
    const float* W2 = (const float*)d_in[4];
    const float* B2 = (const float*)d_in[5];
    const float* W3 = (const float*)d_in[6];
    const float* B3 = (const float*)d_in[7];
    float* out = (float*)d_out;

    const int B = in_sizes[0] / DD;   // 262144

    dim3 grid((B + CHUNK - 1) / CHUNK, NE);
    moe_routed_kernel<<<grid, dim3(BLOCK), 0, stream>>>(
        X, S, W1, B1, W2, B2, W3, B3, out, B);
}

// Round 3
// 108.266 us; speedup vs baseline: 1.5653x; 1.5653x over previous
//
#include <hip/hip_runtime.h>
#include <stdint.h>

#define NE     7
#define DD     64
#define NDC    3
#define BLOCK  256
#define CHUNK  1792
#define WROWS  36            // dwords per packed weight row (32 pairs + bias + pad)
#define EROWS  131           // 64 (L1 j) + 64 (L2 j) + 3 (L3 c)
#define ESZ    (EROWS*WROWS) // dwords per expert

typedef __fp16 h2_t __attribute__((ext_vector_type(2)));

__device__ __forceinline__ float fdot2(uint32_t a, uint32_t b, float c) {
  h2_t ha = __builtin_bit_cast(h2_t, a);
  h2_t hb = __builtin_bit_cast(h2_t, b);
#if __has_builtin(__builtin_amdgcn_fdot2)
  return __builtin_amdgcn_fdot2(ha, hb, c, false);
#else
  return c + (float)ha[0] * (float)hb[0] + (float)ha[1] * (float)hb[1];
#endif
}

__device__ __forceinline__ uint32_t pkrtz(float a, float b) {
  h2_t h = __builtin_amdgcn_cvt_pkrtz(a, b);
  return __builtin_bit_cast(uint32_t, h);
}

// lgkm-only fence: orders same-wave LDS writes vs reads across the type-punned
// LDS buffer without draining vmcnt (rule #18: sched_barrier after inline-asm waitcnt).
__device__ __forceinline__ void lds_fence() {
  asm volatile("s_waitcnt lgkmcnt(0)" ::: "memory");
  __builtin_amdgcn_sched_barrier(0);
}

// ---------------- weight pre-pack: fp32 [k][j] -> fp16-pair rows ----------------
__global__ void pack_w(const float* __restrict__ W1, const float* __restrict__ B1,
                       const float* __restrict__ W2, const float* __restrict__ B2,
                       const float* __restrict__ W3, const float* __restrict__ B3,
                       uint32_t* __restrict__ ws) {
  const int e = blockIdx.x;
  for (int r = threadIdx.x; r < EROWS; r += blockDim.x) {
    const float* Wsrc; int ncol, col; float bias;
    if (r < 64)       { Wsrc = W1 + e*DD*DD;  ncol = DD;  col = r;       bias = B1[e*DD  + col]; }
    else if (r < 128) { Wsrc = W2 + e*DD*DD;  ncol = DD;  col = r - 64;  bias = B2[e*DD  + col]; }
    else              { Wsrc = W3 + e*DD*NDC; ncol = NDC; col = r - 128; bias = B3[e*NDC + col]; }
    uint32_t* dst = ws + (size_t)e*ESZ + r*WROWS;
    for (int kk = 0; kk < 32; ++kk)
      dst[kk] = pkrtz(Wsrc[(2*kk)*ncol + col], Wsrc[(2*kk + 1)*ncol + col]);
    dst[32] = __float_as_uint(bias);
  }
}

// ---------------- main: compact-by-expert, lane=row, s_load weight stream ----------------
__global__ __launch_bounds__(BLOCK) void moe_main(
    const float* __restrict__ X, const int* __restrict__ S,
    const uint32_t* __restrict__ ws, float* __restrict__ out, int B)
{
  __shared__ int list[CHUNK];
  __shared__ int cnt;
  __shared__ uint32_t xh[4][DD*33];   // per-wave x/h buffer (fp16 pairs), 8448 B each

  const int e    = blockIdx.y;
  const int tid  = threadIdx.x;
  const int wv   = tid >> 6;
  const int lane = tid & 63;
  const int base = blockIdx.x * CHUNK;

  if (tid == 0) cnt = 0;
  __syncthreads();
  const int lim = min(CHUNK, B - base);
  for (int i = tid; i < lim; i += BLOCK) {
    const int row = base + i;
    if (S[row] == e) list[atomicAdd(&cnt, 1)] = row;
  }
  __syncthreads();
  const int n = cnt;
  if (n == 0) return;

  const uint32_t* __restrict__ we = ws + (size_t)e*ESZ;
  uint32_t*  __restrict__ xb  = xh[wv];
  __fp16*    __restrict__ xbh = (__fp16*)xb;

  // each wave owns 64-row segments, strided by 256 across the 4 waves
  for (int s = wv*64; s < n; s += 4*64) {

    // ---- stage x: 4 rows per iter, 16 lanes per row (coalesced), pack to fp16 pairs ----
    const int q = lane & 15;
    for (int it = 0; it < 16; ++it) {
      const int rl    = it*4 + (lane >> 4);
      const int entry = min(s + rl, n - 1);
      const int row   = list[entry];
      const float4 v  = *(const float4*)(X + (size_t)row*DD + q*4);
      xb[rl*33 + 2*q]     = pkrtz(v.x, v.y);
      xb[rl*33 + 2*q + 1] = pkrtz(v.z, v.w);
    }

    // ---- x -> registers (lane = row), conflict-free (33-dword stride) ----
    uint32_t xp[32];
    #pragma unroll
    for (int kk = 0; kk < 32; ++kk) xp[kk] = xb[lane*33 + kk];
    lds_fence();

    // ---- layer 1: per output j, weights via uniform s_load, 4 indep acc chains ----
    #pragma unroll 2
    for (int j = 0; j < DD; ++j) {
      const uint32_t* wr = we + j*WROWS;
      float a0 = 0.f, a1 = 0.f, a2 = 0.f, a3 = __uint_as_float(wr[32]);
      #pragma unroll
      for (int kk = 0; kk < 32; kk += 4) {
        a0 = fdot2(xp[kk+0], wr[kk+0], a0);
        a1 = fdot2(xp[kk+1], wr[kk+1], a1);
        a2 = fdot2(xp[kk+2], wr[kk+2], a2);
        a3 = fdot2(xp[kk+3], wr[kk+3], a3);
      }
      const float h = fmaxf((a0 + a1) + (a2 + a3), 0.f);
      xbh[lane*66 + j] = (__fp16)h;            // h1 overwrites x (x already in regs)
    }
    lds_fence();

    // ---- layer 2 ----
    uint32_t hp[32];
    #pragma unroll
    for (int kk = 0; kk < 32; ++kk) hp[kk] = xb[lane*33 + kk];
    lds_fence();

    #pragma unroll 2
    for (int j = 0; j < DD; ++j) {
      const uint32_t* wr = we + (64 + j)*WROWS;
      float a0 = 0.f, a1 = 0.f, a2 = 0.f, a3 = __uint_as_float(wr[32]);
      #pragma unroll
      for (int kk = 0; kk < 32; kk += 4) {
        a0 = fdot2(hp[kk+0], wr[kk+0], a0);
        a1 = fdot2(hp[kk+1], wr[kk+1], a1);
        a2 = fdot2(hp[kk+2], wr[kk+2], a2);
        a3 = fdot2(hp[kk+3], wr[kk+3], a3);
      }
      const float h = fmaxf((a0 + a1) + (a2 + a3), 0.f);
      xbh[lane*66 + j] = (__fp16)h;            // h2 (relu'd) overwrites h1
    }
    lds_fence();

    // ---- layer 3 + softmax (per lane = per row) ----
    uint32_t hq[32];
    #pragma unroll
    for (int kk = 0; kk < 32; ++kk) hq[kk] = xb[lane*33 + kk];

    float l0 = __uint_as_float(we[(128 + 0)*WROWS + 32]);
    float l1 = __uint_as_float(we[(128 + 1)*WROWS + 32]);
    float l2 = __uint_as_float(we[(128 + 2)*WROWS + 32]);
    #pragma unroll
    for (int q8 = 0; q8 < 8; ++q8) {
      const uint32_t* w0 = we + (128 + 0)*WROWS + q8*4;
      const uint32_t* w1 = we + (128 + 1)*WROWS + q8*4;
      const uint32_t* w2 = we + (128 + 2)*WROWS + q8*4;
      #pragma unroll
      for (int u = 0; u < 4; ++u) {
        const uint32_t h = hq[q8*4 + u];
        l0 = fdot2(h, w0[u], l0);
        l1 = fdot2(h, w1[u], l1);
        l2 = fdot2(h, w2[u], l2);
      }
    }

    const int entry = s + lane;
    if (entry < n) {
      const int row = list[entry];
      const float m   = fmaxf(l0, fmaxf(l1, l2));
      const float p0  = __expf(l0 - m);
      const float p1  = __expf(l1 - m);
      const float p2  = __expf(l2 - m);
      const float inv = 1.0f / (p0 + p1 + p2);
      float* o = out + (size_t)row*3;
      o[0] = l0; o[1] = l1; o[2] = l2;
      float* pr = out + (size_t)B*3 + (size_t)row*3;
      pr[0] = p0*inv; pr[1] = p1*inv; pr[2] = p2*inv;
    }
  }
}

extern "C" void kernel_launch(void* const* d_in, const int* in_sizes, int n_in,
                              void* d_out, int out_size, void* d_ws, size_t ws_size,
                              hipStream_t stream)
{
  const float* X  = (const float*)d_in[0];
  const int*   S  = (const int*)d_in[1];
  const float* W1 = (const float*)d_in[2];
  const float* B1 = (const float*)d_in[3];
  const float* W2 = (const float*)d_in[4];
  const float* B2 = (const float*)d_in[5];
  const float* W3 = (const float*)d_in[6];
  const float* B3 = (const float*)d_in[7];
  float* out = (float*)d_out;
  uint32_t* ws = (uint32_t*)d_ws;

  const int B = in_sizes[0] / DD;   // 262144

  pack_w<<<NE, 128, 0, stream>>>(W1, B1, W2, B2, W3, B3, ws);

  dim3 grid((B + CHUNK - 1) / CHUNK, NE);
  moe_main<<<grid, dim3(BLOCK), 0, stream>>>(X, S, ws, out, B);
}

// Round 4
// 41.365 us; speedup vs baseline: 4.0970x; 2.6173x over previous
//
#include <hip/hip_runtime.h>
#include <stdint.h>

#define NE    7
#define DD    64
#define NDC   3
#define BLOCK 256
#define CHUNK 1792
#define NFRAG 18   // W^T A-fragments: 8 (L1) + 8 (L2) + 2 (L3)

typedef __fp16   half8 __attribute__((ext_vector_type(8)));
typedef float    f32x4 __attribute__((ext_vector_type(4)));
typedef uint32_t u32x4 __attribute__((ext_vector_type(4)));
typedef uint32_t u32x2 __attribute__((ext_vector_type(2)));
typedef __fp16   h2_t  __attribute__((ext_vector_type(2)));

__device__ __forceinline__ uint32_t pkrtz(float a, float b) {
  h2_t h = __builtin_amdgcn_cvt_pkrtz(a, b);
  return __builtin_bit_cast(uint32_t, h);
}

__device__ __forceinline__ void lds_fence() {
  asm volatile("s_waitcnt lgkmcnt(0)" ::: "memory");
  __builtin_amdgcn_sched_barrier(0);
}

// ---- pack W^T into A-fragment layout (assumed: two x16 halves, kk = 4*(l>>4)+j per half) ----
// frag f: L1 f=0..7 (nt=f>>1, ks=f&1), L2 f=8..15, L3 f=16..17 (ks=f&1).
// lane l: i-row = n = 16*nt + (l&15);  dword d, half h: kk = 16*(d>>1) + 4*(l>>4) + 2*(d&1) + h;
// k = 32*ks + kk; value = W[k][n]  (W row-major [k][n]).
__global__ void pack_w(const float* __restrict__ W1, const float* __restrict__ W2,
                       const float* __restrict__ W3, uint32_t* __restrict__ ws) {
  const int e = blockIdx.x;
  const float* Wl0 = W1 + e*DD*DD;
  const float* Wl1 = W2 + e*DD*DD;
  const float* Wl2 = W3 + e*DD*NDC;
  for (int idx = threadIdx.x; idx < NFRAG*64; idx += blockDim.x) {
    const int f = idx >> 6, l = idx & 63;
    int layer, fl;
    if (f < 8)       { layer = 0; fl = f; }
    else if (f < 16) { layer = 1; fl = f - 8; }
    else             { layer = 2; fl = f - 16; }
    const int nt = (layer < 2) ? (fl >> 1) : 0;
    const int ks = fl & 1;
    const int n  = nt*16 + (l & 15);
    const int g  = l >> 4;
    uint32_t dst[4];
    for (int d = 0; d < 4; ++d) {
      float v[2];
      for (int h = 0; h < 2; ++h) {
        const int kk = 16*(d>>1) + 4*g + 2*(d&1) + h;
        const int k  = 32*ks + kk;
        float val;
        if (layer == 0)      val = Wl0[k*DD + n];
        else if (layer == 1) val = Wl1[k*DD + n];
        else                 val = (n < NDC) ? Wl2[k*NDC + n] : 0.0f;
        v[h] = val;
      }
      dst[d] = pkrtz(v[0], v[1]);
    }
    uint32_t* p = ws + ((size_t)(e*NFRAG + f)*64 + l)*4;
    p[0]=dst[0]; p[1]=dst[1]; p[2]=dst[2]; p[3]=dst[3];
  }
}

__device__ __forceinline__ f32x4 mfma16(u32x4 a, u32x4 b, f32x4 c) {
  return __builtin_amdgcn_mfma_f32_16x16x32_f16(
      __builtin_bit_cast(half8, a), __builtin_bit_cast(half8, b), c, 0, 0, 0);
}

__global__ __launch_bounds__(BLOCK) void moe_mfma(
    const float* __restrict__ X, const int* __restrict__ S,
    const uint32_t* __restrict__ ws,
    const float* __restrict__ b1, const float* __restrict__ b2,
    const float* __restrict__ b3,
    float* __restrict__ out, int B)
{
  __shared__ int list[CHUNK];
  __shared__ int cnt;
  __shared__ __align__(16) uint16_t hl[4][2][32*64];   // per-wave h1/h2 tiles (4 KB each)

  const int e = blockIdx.y, tid = threadIdx.x;
  const int wv = tid >> 6, lane = tid & 63;
  const int r15 = lane & 15, g = lane >> 4;
  const int base = blockIdx.x * CHUNK;

  if (tid == 0) cnt = 0;
  __syncthreads();
  const int lim = min(CHUNK, B - base);
  for (int i = tid; i < lim; i += BLOCK) {
    const int row = base + i;
    const bool pred = (S[row] == e);
    const unsigned long long mask = __ballot(pred);
    const int prefix = __popcll(mask & ((1ull << lane) - 1ull));
    int bp = 0;
    if (lane == 0 && mask) bp = atomicAdd(&cnt, __popcll(mask));
    bp = __shfl(bp, 0, 64);
    if (pred) list[bp + prefix] = row;
  }
  __syncthreads();
  const int n = cnt;
  if (n == 0) return;

  // resident W^T fragments (72 VGPRs)
  const u32x4* wse = (const u32x4*)ws + (size_t)e*NFRAG*64;
  u32x4 af[NFRAG];
  #pragma unroll
  for (int f = 0; f < NFRAG; ++f) af[f] = wse[f*64 + lane];

  const float bb0 = b3[e*NDC+0], bb1 = b3[e*NDC+1], bb2 = b3[e*NDC+2];
  const float* b1e = b1 + e*DD;
  const float* b2e = b2 + e*DD;

  char* h1b = (char*)&hl[wv][0][0];
  char* h2b = (char*)&hl[wv][1][0];
  const int swz = 16*(lane & 7);   // rows we touch always have (m&7) == (lane&7)

  for (int pass = 0; pass*128 < n; ++pass) {
    const int rel0 = pass*128 + wv*32;
    if (rel0 >= n) continue;

    int rowj[2];
    #pragma unroll
    for (int jt = 0; jt < 2; ++jt)
      rowj[jt] = list[min(rel0 + jt*16 + r15, n-1)];

    // ---- X B'-fragments [jt][ks]: per-lane row = rowj[jt], k-window by g ----
    u32x4 xf[2][2];
    #pragma unroll
    for (int jt = 0; jt < 2; ++jt) {
      const float* xr = X + (size_t)rowj[jt]*DD;
      #pragma unroll
      for (int ks = 0; ks < 2; ++ks) {
        const float4 v0 = *(const float4*)(xr + 32*ks + 4*g);
        const float4 v1 = *(const float4*)(xr + 32*ks + 16 + 4*g);
        u32x4 t = { pkrtz(v0.x,v0.y), pkrtz(v0.z,v0.w),
                    pkrtz(v1.x,v1.y), pkrtz(v1.z,v1.w) };
        xf[jt][ks] = t;
      }
    }

    // ---- Layer 1: D' = W1^T · x^T, relu, pack to h1 ----
    #pragma unroll
    for (int nt = 0; nt < 4; ++nt) {
      const float4 bv = *(const float4*)(b1e + nt*16 + 4*g);
      #pragma unroll
      for (int jt = 0; jt < 2; ++jt) {
        f32x4 c = { bv.x, bv.y, bv.z, bv.w };
        c = mfma16(af[nt*2+0], xf[jt][0], c);
        c = mfma16(af[nt*2+1], xf[jt][1], c);
        u32x2 w2v = { pkrtz(fmaxf(c[0],0.f), fmaxf(c[1],0.f)),
                      pkrtz(fmaxf(c[2],0.f), fmaxf(c[3],0.f)) };
        const int m = jt*16 + r15;
        *(u32x2*)(h1b + m*128 + ((nt*32 + 8*g) ^ swz)) = w2v;
      }
    }
    lds_fence();

    // ---- h1 -> B'-fragments ----
    u32x4 hf[2][2];
    #pragma unroll
    for (int jt = 0; jt < 2; ++jt) {
      const int m = jt*16 + r15;
      #pragma unroll
      for (int ks = 0; ks < 2; ++ks) {
        u32x2 a = *(const u32x2*)(h1b + m*128 + ((64*ks +      8*g) ^ swz));
        u32x2 b = *(const u32x2*)(h1b + m*128 + ((64*ks + 32 + 8*g) ^ swz));
        u32x4 t = { a[0], a[1], b[0], b[1] };
        hf[jt][ks] = t;
      }
    }

    // ---- Layer 2: D' = W2^T · h1^T, relu, pack to h2 ----
    #pragma unroll
    for (int nt = 0; nt < 4; ++nt) {
      const float4 bv = *(const float4*)(b2e + nt*16 + 4*g);
      #pragma unroll
      for (int jt = 0; jt < 2; ++jt) {
        f32x4 c = { bv.x, bv.y, bv.z, bv.w };
        c = mfma16(af[8 + nt*2+0], hf[jt][0], c);
        c = mfma16(af[8 + nt*2+1], hf[jt][1], c);
        u32x2 w2v = { pkrtz(fmaxf(c[0],0.f), fmaxf(c[1],0.f)),
                      pkrtz(fmaxf(c[2],0.f), fmaxf(c[3],0.f)) };
        const int m = jt*16 + r15;
        *(u32x2*)(h2b + m*128 + ((nt*32 + 8*g) ^ swz)) = w2v;
      }
    }
    lds_fence();

    // ---- h2 -> B'-fragments ----
    u32x4 h2f[2][2];
    #pragma unroll
    for (int jt = 0; jt < 2; ++jt) {
      const int m = jt*16 + r15;
      #pragma unroll
      for (int ks = 0; ks < 2; ++ks) {
        u32x2 a = *(const u32x2*)(h2b + m*128 + ((64*ks +      8*g) ^ swz));
        u32x2 b = *(const u32x2*)(h2b + m*128 + ((64*ks + 32 + 8*g) ^ swz));
        u32x4 t = { a[0], a[1], b[0], b[1] };
        h2f[jt][ks] = t;
      }
    }

    // ---- Layer 3 + softmax: lanes g==0 hold classes 0..2 of row m ----
    #pragma unroll
    for (int jt = 0; jt < 2; ++jt) {
      f32x4 c = { bb0, bb1, bb2, 0.f };
      c = mfma16(af[16], h2f[jt][0], c);
      c = mfma16(af[17], h2f[jt][1], c);
      const int rel = rel0 + jt*16 + r15;
      if (g == 0 && rel < n) {
        const int row = rowj[jt];
        const float l0 = c[0], l1 = c[1], l2 = c[2];
        const float mx  = fmaxf(l0, fmaxf(l1, l2));
        const float p0  = __expf(l0 - mx);
        const float p1  = __expf(l1 - mx);
        const float p2  = __expf(l2 - mx);
        const float inv = 1.0f / (p0 + p1 + p2);
        float* o = out + (size_t)row*3;
        o[0] = l0; o[1] = l1; o[2] = l2;
        float* pr = out + (size_t)B*3 + (size_t)row*3;
        pr[0] = p0*inv; pr[1] = p1*inv; pr[2] = p2*inv;
      }
    }
  }
}

extern "C" void kernel_launch(void* const* d_in, const int* in_sizes, int n_in,
                              void* d_out, int out_size, void* d_ws, size_t ws_size,
                              hipStream_t stream)
{
  const float* X  = (const float*)d_in[0];
  const int*   S  = (const int*)d_in[1];
  const float* W1 = (const float*)d_in[2];
  const float* B1 = (const float*)d_in[3];
  const float* W2 = (const float*)d_in[4];
  const float* B2 = (const float*)d_in[5];
  const float* W3 = (const float*)d_in[6];
  const float* B3 = (const float*)d_in[7];
  float* out = (float*)d_out;
  uint32_t* ws = (uint32_t*)d_ws;

  const int B = in_sizes[0] / DD;   // 262144

  pack_w<<<NE, 256, 0, stream>>>(W1, W2, W3, ws);

  dim3 grid((B + CHUNK - 1) / CHUNK, NE);
  moe_mfma<<<grid, dim3(BLOCK), 0, stream>>>(X, S, ws, B1, B2, B3, out, B);
}

// Round 5
// 39.366 us; speedup vs baseline: 4.3050x; 1.0508x over previous
//
#include <hip/hip_runtime.h>
#include <stdint.h>

#define NE    7
#define DD    64
#define NDC   3
#define BLOCK 256
#define CHUNK 1792
#define NFRAG 18   // W^T A-fragments: 8 (L1) + 8 (L2) + 2 (L3)

typedef __fp16   half8 __attribute__((ext_vector_type(8)));
typedef float    f32x4 __attribute__((ext_vector_type(4)));
typedef uint32_t u32x4 __attribute__((ext_vector_type(4)));
typedef __fp16   h2_t  __attribute__((ext_vector_type(2)));

__device__ __forceinline__ uint32_t pkrtz(float a, float b) {
  h2_t h = __builtin_amdgcn_cvt_pkrtz(a, b);
  return __builtin_bit_cast(uint32_t, h);
}

// ---- pack W^T into A-fragment layout (layout HW-verified in R4) ----
// lane l: row n = l&15; dword d, half h: kk = 16*(d>>1) + 4*(l>>4) + 2*(d&1) + h;
// k = 32*ks + kk; value = W[k][n] (W row-major [k][n]).
__global__ void pack_w(const float* __restrict__ W1, const float* __restrict__ W2,
                       const float* __restrict__ W3, uint32_t* __restrict__ ws) {
  const int e = blockIdx.x;
  const float* Wl0 = W1 + e*DD*DD;
  const float* Wl1 = W2 + e*DD*DD;
  const float* Wl2 = W3 + e*DD*NDC;
  for (int idx = threadIdx.x; idx < NFRAG*64; idx += blockDim.x) {
    const int f = idx >> 6, l = idx & 63;
    int layer, fl;
    if (f < 8)       { layer = 0; fl = f; }
    else if (f < 16) { layer = 1; fl = f - 8; }
    else             { layer = 2; fl = f - 16; }
    const int nt = (layer < 2) ? (fl >> 1) : 0;
    const int ks = fl & 1;
    const int n  = nt*16 + (l & 15);
    const int g  = l >> 4;
    uint32_t dst[4];
    for (int d = 0; d < 4; ++d) {
      float v[2];
      for (int h = 0; h < 2; ++h) {
        const int kk = 16*(d>>1) + 4*g + 2*(d&1) + h;
        const int k  = 32*ks + kk;
        float val;
        if (layer == 0)      val = Wl0[k*DD + n];
        else if (layer == 1) val = Wl1[k*DD + n];
        else                 val = (n < NDC) ? Wl2[k*NDC + n] : 0.0f;
        v[h] = val;
      }
      dst[d] = pkrtz(v[0], v[1]);
    }
    uint32_t* p = ws + ((size_t)(e*NFRAG + f)*64 + l)*4;
    p[0]=dst[0]; p[1]=dst[1]; p[2]=dst[2]; p[3]=dst[3];
  }
}

__device__ __forceinline__ f32x4 mfma16(u32x4 a, u32x4 b, f32x4 c) {
  return __builtin_amdgcn_mfma_f32_16x16x32_f16(
      __builtin_bit_cast(half8, a), __builtin_bit_cast(half8, b), c, 0, 0, 0);
}

// relu + pack two D'-tiles (nt even/odd pair) into one B-fragment for the next layer.
// D' lane layout == B lane layout (m = lane&15 on both sides); n=4g+r -> k slots.
__device__ __forceinline__ u32x4 relu_pack(f32x4 lo, f32x4 hi) {
  u32x4 t = { pkrtz(fmaxf(lo[0],0.f), fmaxf(lo[1],0.f)),
              pkrtz(fmaxf(lo[2],0.f), fmaxf(lo[3],0.f)),
              pkrtz(fmaxf(hi[0],0.f), fmaxf(hi[1],0.f)),
              pkrtz(fmaxf(hi[2],0.f), fmaxf(hi[3],0.f)) };
  return t;
}

__global__ __launch_bounds__(BLOCK) void moe_mfma(
    const float* __restrict__ X, const int* __restrict__ S,
    const uint32_t* __restrict__ ws,
    const float* __restrict__ b1, const float* __restrict__ b2,
    const float* __restrict__ b3,
    float* __restrict__ out, int B)
{
  __shared__ int list[CHUNK];
  __shared__ int cnt;

  const int e = blockIdx.y, tid = threadIdx.x;
  const int wv = tid >> 6, lane = tid & 63;
  const int r15 = lane & 15, g = lane >> 4;
  const int base = blockIdx.x * CHUNK;

  if (tid == 0) cnt = 0;
  __syncthreads();
  const int lim = min(CHUNK, B - base);
  for (int i = tid; i < lim; i += BLOCK) {
    const int row = base + i;
    const bool pred = (S[row] == e);
    const unsigned long long mask = __ballot(pred);
    const int prefix = __popcll(mask & ((1ull << lane) - 1ull));
    int bp = 0;
    if (lane == 0 && mask) bp = atomicAdd(&cnt, __popcll(mask));
    bp = __shfl(bp, 0, 64);
    if (pred) list[bp + prefix] = row;
  }
  __syncthreads();
  const int n = cnt;
  if (n == 0) return;

  // resident W^T fragments (72 VGPRs)
  const u32x4* wse = (const u32x4*)ws + (size_t)e*NFRAG*64;
  u32x4 af[NFRAG];
  #pragma unroll
  for (int f = 0; f < NFRAG; ++f) af[f] = wse[f*64 + lane];

  // per-lane bias fragments: lane needs b[nt*16 + 4g + r]
  f32x4 bv1[4], bv2[4];
  #pragma unroll
  for (int nt = 0; nt < 4; ++nt) {
    const float4 a = *(const float4*)(b1 + e*DD + nt*16 + 4*g);
    const float4 b = *(const float4*)(b2 + e*DD + nt*16 + 4*g);
    bv1[nt] = f32x4{ a.x, a.y, a.z, a.w };
    bv2[nt] = f32x4{ b.x, b.y, b.z, b.w };
  }
  const float bb0 = b3[e*NDC+0], bb1 = b3[e*NDC+1], bb2 = b3[e*NDC+2];

  for (int pass = 0; pass*128 < n; ++pass) {
    const int rel0 = pass*128 + wv*32;
    if (rel0 >= n) continue;

    int rowj[2];
    #pragma unroll
    for (int jt = 0; jt < 2; ++jt)
      rowj[jt] = list[min(rel0 + jt*16 + r15, n-1)];

    // ---- X B'-fragments: per-lane row = rowj[jt], k-window by g ----
    u32x4 xf[2][2];
    #pragma unroll
    for (int jt = 0; jt < 2; ++jt) {
      const float* xr = X + (size_t)rowj[jt]*DD;
      #pragma unroll
      for (int ks = 0; ks < 2; ++ks) {
        const float4 v0 = *(const float4*)(xr + 32*ks + 4*g);
        const float4 v1 = *(const float4*)(xr + 32*ks + 16 + 4*g);
        u32x4 t = { pkrtz(v0.x,v0.y), pkrtz(v0.z,v0.w),
                    pkrtz(v1.x,v1.y), pkrtz(v1.z,v1.w) };
        xf[jt][ks] = t;
      }
    }

    // ---- Layer 1: c[nt][jt] = W1^T x^T + b1 ----
    f32x4 c[4][2];
    #pragma unroll
    for (int nt = 0; nt < 4; ++nt) {
      #pragma unroll
      for (int jt = 0; jt < 2; ++jt) {
        f32x4 acc = bv1[nt];
        acc = mfma16(af[nt*2+0], xf[jt][0], acc);
        acc = mfma16(af[nt*2+1], xf[jt][1], acc);
        c[nt][jt] = acc;
      }
    }

    // ---- relu+pack -> h1 B-fragments (in registers, no LDS) ----
    u32x4 hf[2][2];
    #pragma unroll
    for (int jt = 0; jt < 2; ++jt) {
      hf[jt][0] = relu_pack(c[0][jt], c[1][jt]);
      hf[jt][1] = relu_pack(c[2][jt], c[3][jt]);
    }

    // ---- Layer 2 ----
    #pragma unroll
    for (int nt = 0; nt < 4; ++nt) {
      #pragma unroll
      for (int jt = 0; jt < 2; ++jt) {
        f32x4 acc = bv2[nt];
        acc = mfma16(af[8 + nt*2+0], hf[jt][0], acc);
        acc = mfma16(af[8 + nt*2+1], hf[jt][1], acc);
        c[nt][jt] = acc;
      }
    }

    u32x4 h2f[2][2];
    #pragma unroll
    for (int jt = 0; jt < 2; ++jt) {
      h2f[jt][0] = relu_pack(c[0][jt], c[1][jt]);
      h2f[jt][1] = relu_pack(c[2][jt], c[3][jt]);
    }

    // ---- Layer 3 + softmax: lanes g==0 hold classes 0..2 of row m ----
    #pragma unroll
    for (int jt = 0; jt < 2; ++jt) {
      f32x4 acc = { bb0, bb1, bb2, 0.f };
      acc = mfma16(af[16], h2f[jt][0], acc);
      acc = mfma16(af[17], h2f[jt][1], acc);
      const int rel = rel0 + jt*16 + r15;
      if (g == 0 && rel < n) {
        const int row = rowj[jt];
        const float l0 = acc[0], l1 = acc[1], l2 = acc[2];
        const float mx  = fmaxf(l0, fmaxf(l1, l2));
        const float p0  = __expf(l0 - mx);
        const float p1  = __expf(l1 - mx);
        const float p2  = __expf(l2 - mx);
        const float inv = 1.0f / (p0 + p1 + p2);
        float* o = out + (size_t)row*3;
        o[0] = l0; o[1] = l1; o[2] = l2;
        float* pr = out + (size_t)B*3 + (size_t)row*3;
        pr[0] = p0*inv; pr[1] = p1*inv; pr[2] = p2*inv;
      }
    }
  }
}

extern "C" void kernel_launch(void* const* d_in, const int* in_sizes, int n_in,
                              void* d_out, int out_size, void* d_ws, size_t ws_size,
                              hipStream_t stream)
{
  const float* X  = (const float*)d_in[0];
  const int*   S  = (const int*)d_in[1];
  const float* W1 = (const float*)d_in[2];
  const float* B1 = (const float*)d_in[3];
  const float* W2 = (const float*)d_in[4];
  const float* B2 = (const float*)d_in[5];
  const float* W3 = (const float*)d_in[6];
  const float* B3 = (const float*)d_in[7];
  float* out = (float*)d_out;
  uint32_t* ws = (uint32_t*)d_ws;

  const int B = in_sizes[0] / DD;   // 262144

  pack_w<<<NE, 256, 0, stream>>>(W1, W2, W3, ws);

  dim3 grid((B + CHUNK - 1) / CHUNK, NE);
  moe_mfma<<<grid, dim3(BLOCK), 0, stream>>>(X, S, ws, B1, B2, B3, out, B);
}